// Round 1
// baseline (185.860 us; speedup 1.0000x reference)
//
#include <hip/hip_runtime.h>
#include <math.h>

// Problem constants (match reference)
#define HH 72
#define WW 96
#define NN (HH * WW)      // 6912
#define BB 2
#define CC 16
#define DIST_COEF 0.1f
#define EPSF 1e-8f

// pair-kernel tiling
#define TI 64                       // i-tile per block
#define JBLK 256                    // j's per block (= blockDim)
#define N_IT (NN / TI)              // 108 i-tiles
#define N_JC (NN / JBLK)            // 27 j-chunks
#define PAIR_BLOCKS (BB * N_IT * N_JC)  // 5832
#define BLOCKS_PER_B (N_IT * N_JC)      // 2916

// workspace layout (float offsets)
// acc[0..15]: [2..3]=S1 per b, [4..5]=S2 per b, [6..7]=fns per b (atomics, zero-inited)
#define ACC_OFF   0
#define PART_OFF  16                          // 5832 per-block partials
#define F1N_OFF   (PART_OFF + PAIR_BLOCKS + 8)     // 5856, 16B-aligned
#define F2N_OFF   (F1N_OFF + BB * NN * CC)         // + 221184
#define XYZ1_OFF  (F2N_OFF + BB * NN * CC)
#define XYZ2_OFF  (XYZ1_OFF + BB * NN * 4)
#define XYZ2T_OFF (XYZ2_OFF + BB * NN * 4)

__global__ void init_kernel(float* __restrict__ ws) {
    int t = threadIdx.x;
    if (t < 16) ws[ACC_OFF + t] = 0.0f;
}

__global__ void prep_kernel(const float* __restrict__ f1,
                            const float* __restrict__ f2,
                            const float* __restrict__ d1,
                            const float* __restrict__ d2,
                            const float* __restrict__ pose,
                            const float* __restrict__ yz1,
                            float* __restrict__ ws) {
    int idx = blockIdx.x * blockDim.x + threadIdx.x;   // b*NN + n, grid exact
    int b = idx / NN;
    int n = idx - b * NN;

    const float* f1b = f1 + (size_t)b * CC * NN + n;
    const float* f2b = f2 + (size_t)b * CC * NN + n;
    float v1[CC], v2[CC];
    float s1 = 0.f, s2 = 0.f;
#pragma unroll
    for (int c = 0; c < CC; c++) { v1[c] = f1b[c * NN]; s1 += v1[c] * v1[c]; }
#pragma unroll
    for (int c = 0; c < CC; c++) { v2[c] = f2b[c * NN]; s2 += v2[c] * v2[c]; }
    float n1 = sqrtf(s1), n2 = sqrtf(s2);
    float dd1 = d1[idx], dd2 = d2[idx];
    float m1 = dd1 > 0.f ? 1.f : 0.f;
    float m2 = dd2 > 0.f ? 1.f : 0.f;
    float inv1 = m1 / (n1 + EPSF);
    float inv2 = m2 / (n2 + EPSF);

    float* f1n = ws + F1N_OFF + (size_t)idx * CC;
    float* f2n = ws + F2N_OFF + (size_t)idx * CC;
#pragma unroll
    for (int c = 0; c < CC; c += 4) {
        float4 a = make_float4(v1[c] * inv1, v1[c + 1] * inv1, v1[c + 2] * inv1, v1[c + 3] * inv1);
        float4 bb = make_float4(v2[c] * inv2, v2[c + 1] * inv2, v2[c + 2] * inv2, v2[c + 3] * inv2);
        *(float4*)(f1n + c) = a;
        *(float4*)(f2n + c) = bb;
    }

    float y0 = yz1[n], y1 = yz1[NN + n], y2 = yz1[2 * NN + n];
    float x1x = y0 * dd1, x1y = y1 * dd1, x1z = y2 * dd1;
    float x2x = y0 * dd2, x2y = y1 * dd2, x2z = y2 * dd2;
    const float* P = pose + b * 16;
    float tx = P[0] * x2x + P[1] * x2y + P[2] * x2z + P[3];
    float ty = P[4] * x2x + P[5] * x2y + P[6] * x2z + P[7];
    float tz = P[8] * x2x + P[9] * x2y + P[10] * x2z + P[11];

    *(float4*)(ws + XYZ1_OFF + (size_t)idx * 4)  = make_float4(x1x, x1y, x1z, 0.f);
    *(float4*)(ws + XYZ2_OFF + (size_t)idx * 4)  = make_float4(x2x, x2y, x2z, 0.f);
    *(float4*)(ws + XYZ2T_OFF + (size_t)idx * 4) = make_float4(tx, ty, tz, 0.f);

    // per-batch reductions: S1, S2, fns  (each block lies entirely in one batch: NN = 27*256)
    float lm1 = m1, lm2 = m2, lfns = n1 * m1 + n2 * m2;
#pragma unroll
    for (int off = 32; off > 0; off >>= 1) {
        lm1  += __shfl_down(lm1, off, 64);
        lm2  += __shfl_down(lm2, off, 64);
        lfns += __shfl_down(lfns, off, 64);
    }
    __shared__ float red[3][4];
    int lane = threadIdx.x & 63, wid = threadIdx.x >> 6;
    if (lane == 0) { red[0][wid] = lm1; red[1][wid] = lm2; red[2][wid] = lfns; }
    __syncthreads();
    if (threadIdx.x == 0) {
        float sm1 = red[0][0] + red[0][1] + red[0][2] + red[0][3];
        float sm2 = red[1][0] + red[1][1] + red[1][2] + red[1][3];
        float sfn = red[2][0] + red[2][1] + red[2][2] + red[2][3];
        atomicAdd(ws + ACC_OFF + 2 + b, sm1);
        atomicAdd(ws + ACC_OFF + 4 + b, sm2);
        atomicAdd(ws + ACC_OFF + 6 + b, sfn);
    }
}

__global__ __launch_bounds__(JBLK) void pair_kernel(const float* __restrict__ wsc,
                                                    float* __restrict__ ws) {
    int blk = blockIdx.x;
    int jc = blk % N_JC;
    int rest = blk / N_JC;
    int it = rest % N_IT;
    int b = rest / N_IT;
    int tid = threadIdx.x;

    __shared__ float sA[TI][CC];   // f1n tile
    __shared__ float sX[TI][4];    // xyz1 tile

    int i0 = it * TI;
    const float* f1n_tile = wsc + F1N_OFF + (size_t)(b * NN + i0) * CC;
    ((float4*)sA)[tid] = ((const float4*)f1n_tile)[tid];   // 1024 floats = 256 float4
    if (tid < TI)
        ((float4*)sX)[tid] = *(const float4*)(wsc + XYZ1_OFF + (size_t)(b * NN + i0 + tid) * 4);
    __syncthreads();

    int j = jc * JBLK + tid;
    const float* f2n = wsc + F2N_OFF + (size_t)(b * NN + j) * CC;
    float vB[CC];
#pragma unroll
    for (int c = 0; c < CC; c += 4) {
        float4 t = *(const float4*)(f2n + c);
        vB[c] = t.x; vB[c + 1] = t.y; vB[c + 2] = t.z; vB[c + 3] = t.w;
    }
    float4 x2  = *(const float4*)(wsc + XYZ2_OFF + (size_t)(b * NN + j) * 4);
    float4 x2t = *(const float4*)(wsc + XYZ2T_OFF + (size_t)(b * NN + j) * 4);

    float acc = 0.f;
#pragma unroll 4
    for (int i = 0; i < TI; i++) {
        float dot = 0.f;
#pragma unroll
        for (int c = 0; c < CC; c++) dot += sA[i][c] * vB[c];
        float ax = sX[i][0], ay = sX[i][1], az = sX[i][2];
        float dx = ax - x2t.x, dy = ay - x2t.y, dz = az - x2t.z;
        float dt = dx * dx + dy * dy + dz * dz;
        dx = ax - x2.x; dy = ay - x2.y; dz = az - x2.z;
        float dn = dx * dx + dy * dy + dz * dz;
        float w = __expf(dt * (-1.f / DIST_COEF)) - __expf(dn * (-1.f / DIST_COEF));
        acc += w * dot;
    }

    // block reduce -> per-block partial (no atomics)
#pragma unroll
    for (int off = 32; off > 0; off >>= 1) acc += __shfl_down(acc, off, 64);
    __shared__ float red[4];
    int lane = tid & 63, wid = tid >> 6;
    if (lane == 0) red[wid] = acc;
    __syncthreads();
    if (tid == 0) ws[PART_OFF + blockIdx.x] = red[0] + red[1] + red[2] + red[3];
}

__global__ void finalize_kernel(const float* __restrict__ ws, float* __restrict__ out) {
    int tid = threadIdx.x;
    __shared__ float red[BB][4];
#pragma unroll
    for (int b = 0; b < BB; b++) {
        float acc = 0.f;
        for (int k = tid; k < BLOCKS_PER_B; k += 256)
            acc += ws[PART_OFF + b * BLOCKS_PER_B + k];
#pragma unroll
        for (int off = 32; off > 0; off >>= 1) acc += __shfl_down(acc, off, 64);
        int lane = tid & 63, wid = tid >> 6;
        if (lane == 0) red[b][wid] = acc;
    }
    __syncthreads();
    if (tid == 0) {
        float tot = 0.f, fns = 0.f;
        for (int b = 0; b < BB; b++) {
            float raw = red[b][0] + red[b][1] + red[b][2] + red[b][3];
            float S1 = ws[ACC_OFF + 2 + b];
            float S2 = ws[ACC_OFF + 4 + b];
            tot += -raw / (S1 * S2);
            fns += ws[ACC_OFF + 6 + b];
        }
        out[0] = tot;        // final_loss (== inner_neg, sparse_mode=False)
        out[1] = tot;        // inner_neg
        out[2] = 100.f * fns;
    }
}

extern "C" void kernel_launch(void* const* d_in, const int* in_sizes, int n_in,
                              void* d_out, int out_size, void* d_ws, size_t ws_size,
                              hipStream_t stream) {
    const float* f1   = (const float*)d_in[0];
    const float* f2   = (const float*)d_in[1];
    const float* d1   = (const float*)d_in[2];
    const float* d2   = (const float*)d_in[3];
    const float* pose = (const float*)d_in[4];
    // d_in[5], d_in[6] (img1, img2) unused by the loss
    const float* yz1  = (const float*)d_in[7];
    float* ws  = (float*)d_ws;
    float* out = (float*)d_out;

    init_kernel<<<1, 64, 0, stream>>>(ws);
    prep_kernel<<<(BB * NN) / 256, 256, 0, stream>>>(f1, f2, d1, d2, pose, yz1, ws);
    pair_kernel<<<PAIR_BLOCKS, JBLK, 0, stream>>>(ws, ws);
    finalize_kernel<<<1, 256, 0, stream>>>(ws, out);
}

// Round 2
// 127.052 us; speedup vs baseline: 1.4629x; 1.4629x over previous
//
#include <hip/hip_runtime.h>
#include <math.h>

// Problem constants
#define HH 72
#define WW 96
#define NN (HH * WW)          // 6912
#define BB 2
#define CC 16
#define EPSF 1e-8f

// exp2 formulation: k = exp(-sq/0.1) = 2^(-sq * log2(e)/0.1)
#define S0  14.426950408889634f   // log2(e)/0.1
#define SCL 28.853900817779268f   // 2*S0 (applied to A-side xyz)

// tiling
#define NTILES (NN / 16)          // 432 tiles of 16 points
#define NIG (NTILES / 4)          // 108 i-groups (4 i-tiles per wave)
#define NJC 27                    // j-chunks
#define JT_PER_CHUNK (NTILES / NJC)   // 16 j-tiles per chunk
#define NWAVES (BB * NIG * NJC)   // 5832
#define PAIRBLOCKS (NWAVES / 4)   // 1458 (4 waves/block)
#define PREPBLOCKS (BB * NN / 256) // 54 (27 per batch)

// workspace layout: 6 fragment arrays (shorts), each [BB][NTILES][64 lanes][8 bf16]
#define FRAG_ELEMS ((size_t)BB * NTILES * 64 * 8)  // 442368 shorts each
#define AGRAM_OFF ((size_t)0)
#define AARGS_OFF (1 * FRAG_ELEMS)
#define BG_OFF    (2 * FRAG_ELEMS)
#define BGL_OFF   (3 * FRAG_ELEMS)
#define BT_OFF    (4 * FRAG_ELEMS)
#define BN_OFF    (5 * FRAG_ELEMS)
#define FRAG_TOTAL (6 * FRAG_ELEMS)                // shorts
// float region after frags
#define PART_FOFF (FRAG_TOTAL / 2)                 // 5832 pair partials
#define SRED_FOFF (PART_FOFF + NWAVES)             // 54*3 prep partials
// total ws need: ~5.34 MB

typedef __attribute__((ext_vector_type(8))) short s8v;
typedef __attribute__((ext_vector_type(4))) float f4v;

#if __has_builtin(__builtin_amdgcn_exp2f)
#define EXP2(x) __builtin_amdgcn_exp2f(x)
#else
#define EXP2(x) exp2f(x)
#endif

__device__ __forceinline__ unsigned short f2bf(float f) {
    unsigned u = __builtin_bit_cast(unsigned, f);
    unsigned r = (u + 0x7FFFu + ((u >> 16) & 1u)) >> 16;   // RNE
    return (unsigned short)r;
}
__device__ __forceinline__ float bf2f(unsigned short s) {
    unsigned u = ((unsigned)s) << 16;
    return __builtin_bit_cast(float, u);
}

// write one point's 32-channel pack into MFMA fragment layout:
// lane q*16+m holds channels q*8..q*8+7 of point tile*16+m
__device__ __forceinline__ void write_frag(short* base, int b, int tile, int m,
                                           const unsigned short ch[32]) {
#pragma unroll
    for (int q = 0; q < 4; q++) {
        s8v v;
#pragma unroll
        for (int jj = 0; jj < 8; jj++) v[jj] = (short)ch[q * 8 + jj];
        *(s8v*)(base + ((size_t)(b * NTILES + tile) * 64 + q * 16 + m) * 8) = v;
    }
}

__global__ __launch_bounds__(256) void prep_kernel(const float* __restrict__ f1,
                                                   const float* __restrict__ f2,
                                                   const float* __restrict__ d1,
                                                   const float* __restrict__ d2,
                                                   const float* __restrict__ pose,
                                                   const float* __restrict__ yz1,
                                                   short* __restrict__ frag,
                                                   float* __restrict__ sred) {
    int idx = blockIdx.x * 256 + threadIdx.x;   // b*NN + n (grid exact)
    int b = idx / NN;
    int n = idx - b * NN;
    int tile = n >> 4, m = n & 15;

    const float* f1b = f1 + (size_t)b * CC * NN + n;
    const float* f2b = f2 + (size_t)b * CC * NN + n;
    float v1[CC], v2[CC];
    float s1 = 0.f, s2 = 0.f;
#pragma unroll
    for (int c = 0; c < CC; c++) { v1[c] = f1b[c * NN]; s1 += v1[c] * v1[c]; }
#pragma unroll
    for (int c = 0; c < CC; c++) { v2[c] = f2b[c * NN]; s2 += v2[c] * v2[c]; }
    float n1 = sqrtf(s1), n2 = sqrtf(s2);
    float dd1 = d1[idx], dd2 = d2[idx];
    float m1 = dd1 > 0.f ? 1.f : 0.f;
    float m2 = dd2 > 0.f ? 1.f : 0.f;
    float inv1 = m1 / (n1 + EPSF);
    float inv2 = m2 / (n2 + EPSF);

    unsigned short ch[32];

    // A-gram: [f1h(16), f1l(16)]  (hi/lo split of normalized f1)
#pragma unroll
    for (int c = 0; c < CC; c++) {
        float x = v1[c] * inv1;
        unsigned short h = f2bf(x);
        ch[c] = h;
        ch[16 + c] = f2bf(x - bf2f(h));
    }
    write_frag(frag + AGRAM_OFF, b, tile, m, ch);

    // B-gram hi: [f2h, f2h];  B-gram lo: [f2l, 0]
    unsigned short h2[CC], l2[CC];
#pragma unroll
    for (int c = 0; c < CC; c++) {
        float x = v2[c] * inv2;
        h2[c] = f2bf(x);
        l2[c] = f2bf(x - bf2f(h2[c]));
    }
#pragma unroll
    for (int c = 0; c < CC; c++) { ch[c] = h2[c]; ch[16 + c] = h2[c]; }
    write_frag(frag + BG_OFF, b, tile, m, ch);
#pragma unroll
    for (int c = 0; c < CC; c++) { ch[c] = l2[c]; ch[16 + c] = 0; }
    write_frag(frag + BGL_OFF, b, tile, m, ch);

    // geometry
    float y0 = yz1[n], y1 = yz1[NN + n], y2 = yz1[2 * NN + n];
    float x1x = y0 * dd1, x1y = y1 * dd1, x1z = y2 * dd1;
    float x2x = y0 * dd2, x2y = y1 * dd2, x2z = y2 * dd2;
    const float* P = pose + b * 16;
    float tx = P[0] * x2x + P[1] * x2y + P[2] * x2z + P[3];
    float ty = P[4] * x2x + P[5] * x2y + P[6] * x2z + P[7];
    float tz = P[8] * x2x + P[9] * x2y + P[10] * x2z + P[11];

    // A-args u = [2*S0*x1, a_i, 1], split: [uh(5), ul(5), uh(5), 0*17]
    float u[5] = { SCL * x1x, SCL * x1y, SCL * x1z,
                   -S0 * (x1x * x1x + x1y * x1y + x1z * x1z), 1.f };
    unsigned short uh[5], ul[5];
#pragma unroll
    for (int k = 0; k < 5; k++) { uh[k] = f2bf(u[k]); ul[k] = f2bf(u[k] - bf2f(uh[k])); }
#pragma unroll
    for (int k = 0; k < 5; k++) { ch[k] = uh[k]; ch[5 + k] = ul[k]; ch[10 + k] = uh[k]; }
#pragma unroll
    for (int k = 15; k < 32; k++) ch[k] = 0;
    write_frag(frag + AARGS_OFF, b, tile, m, ch);

    // B-args vt = [x2t, 1, bt], vn = [x2, 1, bn]; pack [vh(5), vh(5), vl(5), 0*17]
    float vt[5] = { tx, ty, tz, 1.f, -S0 * (tx * tx + ty * ty + tz * tz) };
    float vn[5] = { x2x, x2y, x2z, 1.f, -S0 * (x2x * x2x + x2y * x2y + x2z * x2z) };
    unsigned short vh[5], vl[5];
#pragma unroll
    for (int k = 0; k < 5; k++) { vh[k] = f2bf(vt[k]); vl[k] = f2bf(vt[k] - bf2f(vh[k])); }
#pragma unroll
    for (int k = 0; k < 5; k++) { ch[k] = vh[k]; ch[5 + k] = vh[k]; ch[10 + k] = vl[k]; }
    // ch[15..31] still 0
    write_frag(frag + BT_OFF, b, tile, m, ch);
#pragma unroll
    for (int k = 0; k < 5; k++) { vh[k] = f2bf(vn[k]); vl[k] = f2bf(vn[k] - bf2f(vh[k])); }
#pragma unroll
    for (int k = 0; k < 5; k++) { ch[k] = vh[k]; ch[5 + k] = vh[k]; ch[10 + k] = vl[k]; }
    write_frag(frag + BN_OFF, b, tile, m, ch);

    // per-block reduction of S1, S2, fns (each block entirely within one batch)
    float lm1 = m1, lm2 = m2, lfns = n1 * m1 + n2 * m2;
#pragma unroll
    for (int off = 32; off > 0; off >>= 1) {
        lm1  += __shfl_down(lm1, off, 64);
        lm2  += __shfl_down(lm2, off, 64);
        lfns += __shfl_down(lfns, off, 64);
    }
    __shared__ float red[3][4];
    int lane = threadIdx.x & 63, wv = threadIdx.x >> 6;
    if (lane == 0) { red[0][wv] = lm1; red[1][wv] = lm2; red[2][wv] = lfns; }
    __syncthreads();
    if (threadIdx.x == 0) {
        sred[blockIdx.x * 3 + 0] = red[0][0] + red[0][1] + red[0][2] + red[0][3];
        sred[blockIdx.x * 3 + 1] = red[1][0] + red[1][1] + red[1][2] + red[1][3];
        sred[blockIdx.x * 3 + 2] = red[2][0] + red[2][1] + red[2][2] + red[2][3];
    }
}

__global__ __launch_bounds__(256) void pair_kernel(const short* __restrict__ frag,
                                                   float* __restrict__ part) {
    int lane = threadIdx.x & 63;
    int wid = blockIdx.x * 4 + (threadIdx.x >> 6);
    int b = wid / (NIG * NJC);
    int r = wid - b * (NIG * NJC);
    int ig = r / NJC;
    int jc = r - ig * NJC;

    const s8v* AG  = (const s8v*)(frag + AGRAM_OFF);
    const s8v* AA  = (const s8v*)(frag + AARGS_OFF);
    const s8v* BG  = (const s8v*)(frag + BG_OFF);
    const s8v* BGL = (const s8v*)(frag + BGL_OFF);
    const s8v* BT  = (const s8v*)(frag + BT_OFF);
    const s8v* BN  = (const s8v*)(frag + BN_OFF);

    s8v ag[4], aa[4];
    int it0 = ig * 4;
#pragma unroll
    for (int t = 0; t < 4; t++) {
        size_t ai = (size_t)(b * NTILES + it0 + t) * 64 + lane;
        ag[t] = AG[ai];
        aa[t] = AA[ai];
    }

    float loss = 0.f;
    int jt0 = jc * JT_PER_CHUNK;
    f4v z = { 0.f, 0.f, 0.f, 0.f };
    for (int jj = 0; jj < JT_PER_CHUNK; jj++) {
        size_t bi = (size_t)(b * NTILES + jt0 + jj) * 64 + lane;
        s8v bg = BG[bi], bgl = BGL[bi], bt = BT[bi], bn = BN[bi];
#pragma unroll
        for (int t = 0; t < 4; t++) {
            f4v g  = __builtin_amdgcn_mfma_f32_16x16x32_bf16(ag[t], bg,  z, 0, 0, 0);
            g      = __builtin_amdgcn_mfma_f32_16x16x32_bf16(ag[t], bgl, g, 0, 0, 0);
            f4v at = __builtin_amdgcn_mfma_f32_16x16x32_bf16(aa[t], bt,  z, 0, 0, 0);
            f4v an = __builtin_amdgcn_mfma_f32_16x16x32_bf16(aa[t], bn,  z, 0, 0, 0);
#pragma unroll
            for (int e = 0; e < 4; e++) {
                float xt = fminf(at[e], 0.f);   // relu clamp on sq (exp2 arg <= 0)
                float xn = fminf(an[e], 0.f);
                loss += (EXP2(xt) - EXP2(xn)) * g[e];
            }
        }
    }
#pragma unroll
    for (int off = 32; off > 0; off >>= 1) loss += __shfl_down(loss, off, 64);
    if (lane == 0) part[wid] = loss;
}

__global__ __launch_bounds__(256) void finalize_kernel(const float* __restrict__ wsF,
                                                       float* __restrict__ out) {
    int tid = threadIdx.x;
    __shared__ float red[BB][4];
#pragma unroll
    for (int b = 0; b < BB; b++) {
        float acc = 0.f;
        for (int k = tid; k < NWAVES / BB; k += 256)
            acc += wsF[PART_FOFF + (size_t)b * (NWAVES / BB) + k];
#pragma unroll
        for (int off = 32; off > 0; off >>= 1) acc += __shfl_down(acc, off, 64);
        int lane = tid & 63, wv = tid >> 6;
        if (lane == 0) red[b][wv] = acc;
    }
    __syncthreads();
    if (tid == 0) {
        float tot = 0.f, fns = 0.f;
        for (int b = 0; b < BB; b++) {
            float raw = red[b][0] + red[b][1] + red[b][2] + red[b][3];
            float S1 = 0.f, S2 = 0.f, fb = 0.f;
            for (int k = 0; k < PREPBLOCKS / BB; k++) {
                size_t o = SRED_FOFF + (size_t)(b * (PREPBLOCKS / BB) + k) * 3;
                S1 += wsF[o + 0];
                S2 += wsF[o + 1];
                fb += wsF[o + 2];
            }
            tot += -raw / (S1 * S2);
            fns += fb;
        }
        out[0] = tot;    // final_loss
        out[1] = tot;    // inner_neg
        out[2] = 100.f * fns;
    }
}

extern "C" void kernel_launch(void* const* d_in, const int* in_sizes, int n_in,
                              void* d_out, int out_size, void* d_ws, size_t ws_size,
                              hipStream_t stream) {
    const float* f1   = (const float*)d_in[0];
    const float* f2   = (const float*)d_in[1];
    const float* d1   = (const float*)d_in[2];
    const float* d2   = (const float*)d_in[3];
    const float* pose = (const float*)d_in[4];
    const float* yz1  = (const float*)d_in[7];
    short* frag = (short*)d_ws;
    float* wsF  = (float*)d_ws;
    float* out  = (float*)d_out;

    prep_kernel<<<PREPBLOCKS, 256, 0, stream>>>(f1, f2, d1, d2, pose, yz1,
                                                frag, wsF + SRED_FOFF);
    pair_kernel<<<PAIRBLOCKS, 256, 0, stream>>>(frag, wsF + PART_FOFF);
    finalize_kernel<<<1, 256, 0, stream>>>(wsF, out);
}